// Round 3
// baseline (281.214 us; speedup 1.0000x reference)
//
#include <hip/hip_runtime.h>

// ConditionalFeedForward (gpt-fast MoE FFN), MI355X.
// Dtype evidence (R1+R2): inputs fp32 (bf16-misread => NaN; on-device
// detector voted fp32), output fp32 (bf16-packed write failed with the exact
// mispairing error signature). Layouts per reference:
//   x[T][H], idx[T][K], gate[E][I][H], up[E][H][I], down[E][I][H]
//   out[t][a][h] = sum_o silu(x.gate_row_o)*(x.down_row_o) * up[e][h][o]
// Strategy: group (token,slot) pairs by expert; stream every weight row from
// HBM exactly once (276 MB fp32 total => ~44 us HBM floor).
#define NE 8        // experts
#define HD 1024     // hidden
#define IW 2816     // intermediate
#define NT 16       // tokens
#define TK 2        // top-k
#define NP (NT*TK)  // 32 (token, slot) pairs

__device__ __forceinline__ float wave_sum(float v) {
    #pragma unroll
    for (int off = 32; off > 0; off >>= 1) v += __shfl_xor(v, off, 64);
    return v;
}

// Phase 1: hbuf[p][o] = silu(x[t].gate[e][o]) * (x[t].down[e][o])
// One wave per o-row. Each float4 load is 64 lanes x 16 B contiguous (1 KB).
__global__ __launch_bounds__(256) void moe_phase1(
    const float* __restrict__ x,      // [NT][HD]
    const int*   __restrict__ idx,    // [NT][TK]
    const float* __restrict__ gate,   // [NE][IW][HD]
    const float* __restrict__ down,   // [NE][IW][HD]
    float*       __restrict__ hbuf)   // [NP][IW] fp32 scratch
{
    __shared__ int s_list[NP];
    __shared__ int s_n;
    const int e = blockIdx.y;
    if (threadIdx.x == 0) {
        int n = 0;
        for (int p = 0; p < NP; ++p) if (idx[p] == e) s_list[n++] = p;
        s_n = n;
    }
    __syncthreads();
    const int npl = s_n;
    if (npl == 0) return;

    const int wave = threadIdx.x >> 6;
    const int lane = threadIdx.x & 63;

    for (int o = blockIdx.x * 4 + wave; o < IW; o += gridDim.x * 4) {
        const float* grow = gate + ((size_t)e * IW + o) * HD;
        const float* drow = down + ((size_t)e * IW + o) * HD;
        float gw[16], dw[16];
        #pragma unroll
        for (int c = 0; c < 4; ++c) {   // HD = 4 * 256; chunk = c*256 + lane*4
            float4 gv = *(const float4*)(grow + c * 256 + lane * 4);
            float4 dv = *(const float4*)(drow + c * 256 + lane * 4);
            gw[4*c+0]=gv.x; gw[4*c+1]=gv.y; gw[4*c+2]=gv.z; gw[4*c+3]=gv.w;
            dw[4*c+0]=dv.x; dw[4*c+1]=dv.y; dw[4*c+2]=dv.z; dw[4*c+3]=dv.w;
        }

        for (int n = 0; n < npl; ++n) {
            const int p = s_list[n];
            const int t = p >> 1;   // TK == 2
            const float* xrow = x + (size_t)t * HD;
            float ag = 0.f, ad = 0.f;
            #pragma unroll
            for (int c = 0; c < 4; ++c) {
                float4 xv = *(const float4*)(xrow + c * 256 + lane * 4);
                ag += xv.x*gw[4*c+0] + xv.y*gw[4*c+1] + xv.z*gw[4*c+2] + xv.w*gw[4*c+3];
                ad += xv.x*dw[4*c+0] + xv.y*dw[4*c+1] + xv.z*dw[4*c+2] + xv.w*dw[4*c+3];
            }
            ag = wave_sum(ag);
            ad = wave_sum(ad);
            if (lane == 0) {
                float s = ag / (1.f + __expf(-ag));   // silu
                hbuf[(size_t)p * IW + o] = s * ad;
            }
        }
    }
}

// Phase 2: out[p][h] = sum_o hbuf[p][o] * up[e][h][o]
// One wave per h-row; 44 up-weights/lane in registers; hbuf rows hit L2.
__global__ __launch_bounds__(256) void moe_phase2(
    const float* __restrict__ up,     // [NE][HD][IW]
    const int*   __restrict__ idx,    // [NT][TK]
    const float* __restrict__ hbuf,   // [NP][IW]
    float*       __restrict__ out)    // [NP][HD] fp32
{
    __shared__ int s_list[NP];
    __shared__ int s_n;
    const int e = blockIdx.y;
    if (threadIdx.x == 0) {
        int n = 0;
        for (int p = 0; p < NP; ++p) if (idx[p] == e) s_list[n++] = p;
        s_n = n;
    }
    __syncthreads();
    const int npl = s_n;
    if (npl == 0) return;

    const int wave = threadIdx.x >> 6;
    const int lane = threadIdx.x & 63;

    for (int h = blockIdx.x * 4 + wave; h < HD; h += gridDim.x * 4) {
        const float* urow = up + ((size_t)e * HD + h) * IW;
        float w[44];                          // IW = 2816 = 11 * 256
        #pragma unroll
        for (int c = 0; c < 11; ++c) {
            float4 uv = *(const float4*)(urow + c * 256 + lane * 4);
            w[4*c+0]=uv.x; w[4*c+1]=uv.y; w[4*c+2]=uv.z; w[4*c+3]=uv.w;
        }

        for (int n = 0; n < npl; ++n) {
            const int p = s_list[n];
            const float* hrow = hbuf + (size_t)p * IW;
            float acc = 0.f;
            #pragma unroll
            for (int c = 0; c < 11; ++c) {
                float4 hv = *(const float4*)(hrow + c * 256 + lane * 4);
                acc += w[4*c+0]*hv.x + w[4*c+1]*hv.y + w[4*c+2]*hv.z + w[4*c+3]*hv.w;
            }
            acc = wave_sum(acc);
            if (lane == 0) out[(size_t)p * HD + h] = acc;
        }
    }
}

extern "C" void kernel_launch(void* const* d_in, const int* in_sizes, int n_in,
                              void* d_out, int out_size, void* d_ws, size_t ws_size,
                              hipStream_t stream) {
    const float* x    = (const float*)d_in[0];
    const int*   idx  = (const int*)  d_in[1];
    const float* gate = (const float*)d_in[2];
    const float* up   = (const float*)d_in[3];
    const float* down = (const float*)d_in[4];
    float* hbuf = (float*)d_ws;              // 32*2816*4 = 360448 B scratch
    float* out  = (float*)d_out;             // [16][2][1024] fp32

    moe_phase1<<<dim3(176, NE), dim3(256), 0, stream>>>(x, idx, gate, down, hbuf);
    moe_phase2<<<dim3(64,  NE), dim3(256), 0, stream>>>(up, idx, hbuf, out);
}

// Round 4
// 278.971 us; speedup vs baseline: 1.0080x; 1.0080x over previous
//
#include <hip/hip_runtime.h>

// ConditionalFeedForward (gpt-fast MoE FFN), MI355X. fp32 in/out (R1/R2 evidence).
//   x[T][H], idx[T][K], gate[E][I][H], up[E][H][I], down[E][I][H]
//   hbuf[p][o] = silu(x.gate_row) * (x.down_row);  out[p][h] = hbuf[p].up_row
// R3 counters: latency-bound (VALUBusy 11%, occ 40%, L3-resident replays at
// 2.3 TB/s). R4 change: one weight row per wave -> 4x wave parallelism
// (phase1 88 waves/CU queued, phase2 32/CU) to overlap L3 latency stalls.
#define NE 8
#define HD 1024
#define IW 2816
#define NT 16
#define TK 2
#define NP (NT*TK)

__device__ __forceinline__ float wave_sum(float v) {
    #pragma unroll
    for (int off = 32; off > 0; off >>= 1) v += __shfl_xor(v, off, 64);
    return v;
}

// Phase 1: one wave per (expert, o-row). 8 contiguous 16B loads per wave
// (gate row + down row), then per-pair dot + butterfly reduction.
__global__ __launch_bounds__(256) void moe_phase1(
    const float* __restrict__ x,      // [NT][HD]
    const int*   __restrict__ idx,    // [NT][TK]
    const float* __restrict__ gate,   // [NE][IW][HD]
    const float* __restrict__ down,   // [NE][IW][HD]
    float*       __restrict__ hbuf)   // [NP][IW]
{
    __shared__ int s_list[NP];
    __shared__ int s_n;
    const int e = blockIdx.y;
    if (threadIdx.x == 0) {
        int n = 0;
        for (int p = 0; p < NP; ++p) if (idx[p] == e) s_list[n++] = p;
        s_n = n;
    }
    __syncthreads();
    const int npl = s_n;
    if (npl == 0) return;

    const int wave = threadIdx.x >> 6;
    const int lane = threadIdx.x & 63;
    const int o = blockIdx.x * 4 + wave;          // gridDim.x = IW/4 = 704
    if (o >= IW) return;

    const float* grow = gate + ((size_t)e * IW + o) * HD;
    const float* drow = down + ((size_t)e * IW + o) * HD;
    float gw[16], dw[16];
    #pragma unroll
    for (int c = 0; c < 4; ++c) {                  // HD = 4*256; 1KB/load/wave
        float4 gv = *(const float4*)(grow + c * 256 + lane * 4);
        float4 dv = *(const float4*)(drow + c * 256 + lane * 4);
        gw[4*c+0]=gv.x; gw[4*c+1]=gv.y; gw[4*c+2]=gv.z; gw[4*c+3]=gv.w;
        dw[4*c+0]=dv.x; dw[4*c+1]=dv.y; dw[4*c+2]=dv.z; dw[4*c+3]=dv.w;
    }

    for (int n = 0; n < npl; ++n) {
        const int p = s_list[n];
        const float* xrow = x + (size_t)(p >> 1) * HD;   // TK==2
        float ag = 0.f, ad = 0.f;
        #pragma unroll
        for (int c = 0; c < 4; ++c) {
            float4 xv = *(const float4*)(xrow + c * 256 + lane * 4);
            ag += xv.x*gw[4*c+0] + xv.y*gw[4*c+1] + xv.z*gw[4*c+2] + xv.w*gw[4*c+3];
            ad += xv.x*dw[4*c+0] + xv.y*dw[4*c+1] + xv.z*dw[4*c+2] + xv.w*dw[4*c+3];
        }
        ag = wave_sum(ag);
        ad = wave_sum(ad);
        if (lane == 0) {
            float s = ag / (1.f + __expf(-ag));   // silu
            hbuf[(size_t)p * IW + o] = s * ad;
        }
    }
}

// Phase 2: one wave per (expert, h-row). 11 contiguous 16B loads (up row),
// hbuf rows are L2-resident (360 KB).
__global__ __launch_bounds__(256) void moe_phase2(
    const float* __restrict__ up,     // [NE][HD][IW]
    const int*   __restrict__ idx,
    const float* __restrict__ hbuf,   // [NP][IW]
    float*       __restrict__ out)    // [NP][HD]
{
    __shared__ int s_list[NP];
    __shared__ int s_n;
    const int e = blockIdx.y;
    if (threadIdx.x == 0) {
        int n = 0;
        for (int p = 0; p < NP; ++p) if (idx[p] == e) s_list[n++] = p;
        s_n = n;
    }
    __syncthreads();
    const int npl = s_n;
    if (npl == 0) return;

    const int wave = threadIdx.x >> 6;
    const int lane = threadIdx.x & 63;
    const int h = blockIdx.x * 4 + wave;          // gridDim.x = HD/4 = 256
    if (h >= HD) return;

    const float* urow = up + ((size_t)e * HD + h) * IW;
    float w[44];                                   // IW = 11*256
    #pragma unroll
    for (int c = 0; c < 11; ++c) {
        float4 uv = *(const float4*)(urow + c * 256 + lane * 4);
        w[4*c+0]=uv.x; w[4*c+1]=uv.y; w[4*c+2]=uv.z; w[4*c+3]=uv.w;
    }

    for (int n = 0; n < npl; ++n) {
        const int p = s_list[n];
        const float* hrow = hbuf + (size_t)p * IW;
        float acc = 0.f;
        #pragma unroll
        for (int c = 0; c < 11; ++c) {
            float4 hv = *(const float4*)(hrow + c * 256 + lane * 4);
            acc += w[4*c+0]*hv.x + w[4*c+1]*hv.y + w[4*c+2]*hv.z + w[4*c+3]*hv.w;
        }
        acc = wave_sum(acc);
        if (lane == 0) out[(size_t)p * HD + h] = acc;
    }
}

extern "C" void kernel_launch(void* const* d_in, const int* in_sizes, int n_in,
                              void* d_out, int out_size, void* d_ws, size_t ws_size,
                              hipStream_t stream) {
    const float* x    = (const float*)d_in[0];
    const int*   idx  = (const int*)  d_in[1];
    const float* gate = (const float*)d_in[2];
    const float* up   = (const float*)d_in[3];
    const float* down = (const float*)d_in[4];
    float* hbuf = (float*)d_ws;              // 32*2816*4 = 360448 B scratch
    float* out  = (float*)d_out;             // [16][2][1024]

    moe_phase1<<<dim3(IW/4, NE), dim3(256), 0, stream>>>(x, idx, gate, down, hbuf);
    moe_phase2<<<dim3(HD/4, NE), dim3(256), 0, stream>>>(up, idx, hbuf, out);
}